// Round 12
// baseline (1095.654 us; speedup 1.0000x reference)
//
#include <hip/hip_runtime.h>
#include <hip/hip_bf16.h>

// ZINC GINE inner, round 12: occupancy fixes for the barrier-bound GEMM kernels.
// - k_mlp/k_mlp1: 1024 thr, 256-row tiles -> 16 waves/CU (was 8), half the
//   barriers per row. (r11: MfmaUtil 8.6%, Occ 18.8%, latency-bound.)
// - k_emsg: 512 thr, 128-edge tiles -> 2 blocks/CU, 16 waves/CU.

#define BNEPS 1e-5f
#define LDA 136   // 128 + 8 shorts pad
#define SCAN_NB 240

typedef __attribute__((ext_vector_type(8))) short bf16x8;
typedef __attribute__((ext_vector_type(8))) unsigned short u16x8;
typedef __attribute__((ext_vector_type(4))) float f32x4;

__device__ inline short f2bf(float f) {
    __hip_bfloat16 h = __float2bfloat16(f);
    return *reinterpret_cast<short*>(&h);
}
__device__ inline unsigned short f2bfu(float f) {
    __hip_bfloat16 h = __float2bfloat16(f);
    return *reinterpret_cast<unsigned short*>(&h);
}
__device__ inline float bf2f(unsigned short u) {
    union { unsigned int i; float f; } v; v.i = ((unsigned int)u) << 16; return v.f;
}

// ---------------- prep: transpose 10 f32 [128,128] weights -> bf16 W^T ----------------
__global__ __launch_bounds__(256) void k_prep(
    const float* __restrict__ m1W2, const float* __restrict__ beW2,
    const float* __restrict__ mW1, const float* __restrict__ mW2,
    short* __restrict__ out)
{
    __shared__ float tileS[64][65];
    int b = blockIdx.x, mat = b >> 2, t = b & 3;
    const float* Wsrc;
    if (mat == 0) Wsrc = m1W2;
    else {
        int l = (mat - 1) / 3, which = (mat - 1) % 3;
        Wsrc = (which == 0) ? beW2 + (size_t)l * 16384
             : (which == 1) ? mW1 + (size_t)l * 16384
             :                mW2 + (size_t)l * 16384;
    }
    short* dst = out + (size_t)mat * 16384;
    int tr = (t >> 1) * 64, tc = (t & 1) * 64;
    for (int i = threadIdx.x; i < 4096; i += 256) {
        int r = i >> 6, c = i & 63;
        tileS[r][c] = Wsrc[(size_t)(tr + r) * 128 + (tc + c)];
    }
    __syncthreads();
    for (int i = threadIdx.x; i < 4096; i += 256) {
        int n = i >> 6, k = i & 63;
        dst[(size_t)(tc + n) * 128 + (tr + k)] = f2bf(tileS[k][n]);
    }
}

// ---------------- prep: layer-1 W1 [28,128] -> bf16 W^T padded K=32 ----------------
__global__ __launch_bounds__(256) void k_prep1(
    const float* __restrict__ W1, short* __restrict__ out)
{
    for (int i = threadIdx.x; i < 128 * 32; i += 256) {
        int n = i >> 5, k = i & 31;
        out[i] = (k < 28) ? f2bf(W1[(size_t)k * 128 + n]) : (short)0;
    }
}

// ---------------- prep: layer-1 edge W2 [28,28] -> bf16 W^T padded [32][32] ----------------
__global__ __launch_bounds__(256) void k_prep28(
    const float* __restrict__ W2, short* __restrict__ out)
{
    for (int i = threadIdx.x; i < 32 * 32; i += 256) {
        int n = i >> 5, k = i & 31;
        out[i] = (n < 28 && k < 28) ? f2bf(W2[(size_t)k * 28 + n]) : (short)0;
    }
}

// ---------------- prep: x [N,28] f32 -> x_bf [N,32] bf16 ----------------
__global__ __launch_bounds__(256) void k_prepx(
    const float* __restrict__ x, unsigned short* __restrict__ xbf, int N)
{
    int total = N * 32;
    for (int i = blockIdx.x * 256 + threadIdx.x; i < total; i += gridDim.x * 256) {
        int n = i >> 5, c = i & 31;
        xbf[i] = (c < 28) ? f2bfu(x[(size_t)n * 28 + c]) : (unsigned short)0;
    }
}

// ---------------- CSR build ----------------
__global__ __launch_bounds__(256) void k_count(
    const int* __restrict__ ei, int* __restrict__ counts, int E)
{
    for (int e = blockIdx.x * 256 + threadIdx.x; e < E; e += gridDim.x * 256)
        atomicAdd(&counts[ei[E + e]], 1);
}

__global__ __launch_bounds__(256) void k_count2(
    const int* __restrict__ s2n, const float* __restrict__ mask,
    int* __restrict__ counts2, int N)
{
    for (int n = blockIdx.x * 256 + threadIdx.x; n < N; n += gridDim.x * 256)
        if (mask[n] != 0.f) atomicAdd(&counts2[s2n[n]], 1);
}

__global__ __launch_bounds__(256) void k_scanA(
    const int* __restrict__ counts, int* __restrict__ bsum, int N, int seg)
{
    __shared__ int red[256];
    int b = blockIdx.x;
    int lo = b * seg, hi = min(lo + seg, N);
    int s = 0;
    for (int i = lo + threadIdx.x; i < hi; i += 256) s += counts[i];
    red[threadIdx.x] = s;
    __syncthreads();
    for (int d = 128; d > 0; d >>= 1) {
        if (threadIdx.x < d) red[threadIdx.x] += red[threadIdx.x + d];
        __syncthreads();
    }
    if (threadIdx.x == 0) bsum[b] = red[0];
}

__global__ __launch_bounds__(256) void k_scanB(
    int* __restrict__ bsum, int nb, int* __restrict__ offs, int N)
{
    __shared__ int sh[256];
    int v = (threadIdx.x < nb) ? bsum[threadIdx.x] : 0;
    sh[threadIdx.x] = v;
    __syncthreads();
    for (int d = 1; d < 256; d <<= 1) {
        int t = (threadIdx.x >= d) ? sh[threadIdx.x - d] : 0;
        __syncthreads();
        sh[threadIdx.x] += t;
        __syncthreads();
    }
    if (threadIdx.x < nb) bsum[threadIdx.x] = sh[threadIdx.x] - v;
    if (threadIdx.x == 0) offs[N] = sh[255];
}

__global__ __launch_bounds__(256) void k_scanC(
    const int* __restrict__ counts, const int* __restrict__ bsum,
    int* __restrict__ offs, int* __restrict__ cursor, int N, int seg)
{
    __shared__ int sh[256];
    int b = blockIdx.x;
    int lo = b * seg, hi = min(lo + seg, N);
    int base = bsum[b];
    for (int t0 = lo; t0 < hi; t0 += 256) {
        int i = t0 + threadIdx.x;
        int v = (i < hi) ? counts[i] : 0;
        sh[threadIdx.x] = v;
        __syncthreads();
        for (int d = 1; d < 256; d <<= 1) {
            int t = (threadIdx.x >= d) ? sh[threadIdx.x - d] : 0;
            __syncthreads();
            sh[threadIdx.x] += t;
            __syncthreads();
        }
        int excl = base + sh[threadIdx.x] - v;
        if (i < hi) { offs[i] = excl; cursor[i] = excl; }
        int tileTotal = sh[255];
        __syncthreads();
        base += tileTotal;
    }
}

__global__ __launch_bounds__(256) void k_scatter(
    const int* __restrict__ ei, const float* __restrict__ ew,
    const float4* __restrict__ ea4,
    int* __restrict__ cursor, int2* __restrict__ pmeta,
    float4* __restrict__ pea4, int E)
{
    for (int e = blockIdx.x * 256 + threadIdx.x; e < E; e += gridDim.x * 256) {
        int d = ei[E + e];
        int pos = atomicAdd(&cursor[d], 1);
        pmeta[pos] = make_int2(ei[e], __float_as_int(ew[e]));
        pea4[pos] = ea4[e];
    }
}

__global__ __launch_bounds__(256) void k_scatter2(
    const int* __restrict__ s2n, const float* __restrict__ mask,
    int* __restrict__ cursor2, int* __restrict__ perm2, int N)
{
    for (int n = blockIdx.x * 256 + threadIdx.x; n < N; n += gridDim.x * 256)
        if (mask[n] != 0.f) {
            int pos = atomicAdd(&cursor2[s2n[n]], 1);
            perm2[pos] = n;
        }
}

// ---------------- hidden edge GEMM: 512 thr, 128-edge tiles (2 blk/CU) ----------------
__global__ __launch_bounds__(512) void k_emsg(
    const float4* __restrict__ pea4,
    const float* __restrict__ W1, const float* __restrict__ b1,
    const short* __restrict__ W2t, const float* __restrict__ b2,
    unsigned short* __restrict__ emsg, const int* __restrict__ offs,
    int n0, int n1)
{
    __shared__ short Bs[128 * LDA];
    __shared__ short As[128 * LDA];
    __shared__ float eas[128][4];
    int e0 = offs[n0], e1 = offs[n1];
    int tid = threadIdx.x;
    for (int i = tid; i < 2048; i += 512) {
        int n = (i * 8) >> 7, k = (i * 8) & 127;
        *(bf16x8*)&Bs[n * LDA + k] = *(const bf16x8*)&W2t[i * 8];
    }
    int j = tid & 127, half = tid >> 7;   // half in [0,4)
    float w10 = W1[j], w11 = W1[128 + j], w12 = W1[256 + j], w13 = W1[384 + j];
    float b1j = b1[j];
    int w = tid >> 6, lane = tid & 63;    // w in [0,8): rows w*16..w*16+15
    int l15 = lane & 15, quad = lane >> 4;
    __syncthreads();

    int numTiles = (e1 - e0 + 127) >> 7;
    for (int tile = blockIdx.x; tile < numTiles; tile += gridDim.x) {
        int base = e0 + tile * 128;
        __syncthreads();
        if (tid < 128) {
            int k = base + tid;
            float4 a = make_float4(0.f, 0.f, 0.f, 0.f);
            if (k < e1) a = pea4[k];
            eas[tid][0] = a.x; eas[tid][1] = a.y; eas[tid][2] = a.z; eas[tid][3] = a.w;
        }
        __syncthreads();
        #pragma unroll
        for (int q = 0; q < 32; ++q) {
            int e = half * 32 + q;
            float t = fmaf(eas[e][0], w10, fmaf(eas[e][1], w11,
                      fmaf(eas[e][2], w12, fmaf(eas[e][3], w13, b1j))));
            As[e * LDA + j] = f2bf(fmaxf(t, 0.f));
        }
        __syncthreads();
        f32x4 acc[8];
        #pragma unroll
        for (int nt = 0; nt < 8; ++nt) acc[nt] = (f32x4){0.f, 0.f, 0.f, 0.f};
        #pragma unroll
        for (int kt = 0; kt < 4; ++kt) {
            bf16x8 af = *(bf16x8*)&As[(w * 16 + l15) * LDA + kt * 32 + quad * 8];
            #pragma unroll
            for (int nt = 0; nt < 8; ++nt) {
                bf16x8 bf = *(bf16x8*)&Bs[(nt * 16 + l15) * LDA + kt * 32 + quad * 8];
                acc[nt] = __builtin_amdgcn_mfma_f32_16x16x32_bf16(af, bf, acc[nt], 0, 0, 0);
            }
        }
        #pragma unroll
        for (int nt = 0; nt < 8; ++nt) {
            int col = nt * 16 + l15;
            float b2c = b2[col];
            #pragma unroll
            for (int r = 0; r < 4; ++r) {
                int row = w * 16 + quad * 4 + r;
                As[row * LDA + col] = f2bf(acc[nt][r] + b2c);
            }
        }
        __syncthreads();
        #pragma unroll
        for (int kk = 0; kk < 4; ++kk) {
            int i = tid + kk * 512;
            int row = (i * 8) >> 7, col = (i * 8) & 127;
            int gr = base + row;
            if (gr < e1)
                *(bf16x8*)&emsg[(size_t)(gr - e0) * 128 + col] = *(bf16x8*)&As[row * LDA + col];
        }
    }
}

// ---------------- layer-1 edge MLP via MFMA ----------------
__global__ __launch_bounds__(256) void k_emsg28_mm(
    const float4* __restrict__ pea4,
    const float* __restrict__ W1, const float* __restrict__ b1,
    const short* __restrict__ W2t28,
    const float* __restrict__ b2,
    unsigned short* __restrict__ emsg28, int E)
{
    __shared__ short Bs[32 * 40];
    __shared__ short As[64 * 40];
    __shared__ float eas[64][4];
    __shared__ float b2s[32];
    int tid = threadIdx.x;
    for (int i = tid; i < 32 * 32; i += 256) {
        int n = i >> 5, k = i & 31;
        Bs[n * 40 + k] = W2t28[i];
    }
    if (tid < 32) b2s[tid] = (tid < 28) ? b2[tid] : 0.f;
    int j = tid & 31, sub = tid >> 5;
    float w10 = 0.f, w11 = 0.f, w12 = 0.f, w13 = 0.f, b1j = 0.f;
    if (j < 28) { w10 = W1[j]; w11 = W1[28 + j]; w12 = W1[56 + j]; w13 = W1[84 + j]; b1j = b1[j]; }
    int w = tid >> 6, lane = tid & 63;
    int l15 = lane & 15, quad = lane >> 4;
    __syncthreads();

    int numTiles = (E + 63) >> 6;
    for (int tile = blockIdx.x; tile < numTiles; tile += gridDim.x) {
        int base = tile * 64;
        __syncthreads();
        if (tid < 64) {
            int k = base + tid;
            float4 a = (k < E) ? pea4[k] : make_float4(0.f, 0.f, 0.f, 0.f);
            eas[tid][0] = a.x; eas[tid][1] = a.y; eas[tid][2] = a.z; eas[tid][3] = a.w;
        }
        __syncthreads();
        #pragma unroll
        for (int q = 0; q < 8; ++q) {
            int e = q * 8 + sub;
            float t = fmaf(eas[e][0], w10, fmaf(eas[e][1], w11,
                      fmaf(eas[e][2], w12, fmaf(eas[e][3], w13, b1j))));
            As[e * 40 + j] = (j < 28) ? f2bf(fmaxf(t, 0.f)) : (short)0;
        }
        __syncthreads();
        f32x4 acc[2];
        acc[0] = (f32x4){0.f, 0.f, 0.f, 0.f};
        acc[1] = (f32x4){0.f, 0.f, 0.f, 0.f};
        bf16x8 af = *(bf16x8*)&As[(w * 16 + l15) * 40 + quad * 8];
        #pragma unroll
        for (int nt = 0; nt < 2; ++nt) {
            bf16x8 bf = *(bf16x8*)&Bs[(nt * 16 + l15) * 40 + quad * 8];
            acc[nt] = __builtin_amdgcn_mfma_f32_16x16x32_bf16(af, bf, acc[nt], 0, 0, 0);
        }
        __syncthreads();
        #pragma unroll
        for (int nt = 0; nt < 2; ++nt) {
            int col = nt * 16 + l15;
            float bb = b2s[col];
            #pragma unroll
            for (int r = 0; r < 4; ++r)
                As[(w * 16 + quad * 4 + r) * 40 + col] = f2bf(acc[nt][r] + bb);
        }
        __syncthreads();
        for (int i = tid; i < 64 * 28; i += 256) {
            int row = i / 28, col = i - row * 28;
            int gr = base + row;
            if (gr < E) emsg28[(size_t)gr * 28 + col] = As[row * 40 + col];
        }
    }
}

// ---------------- gather node-chunk [n0,n1) ----------------
__global__ __launch_bounds__(256) void k_gather(
    const unsigned short* __restrict__ h, const int* __restrict__ offs,
    const int2* __restrict__ pmeta, const unsigned short* __restrict__ emsg,
    unsigned short* __restrict__ a0,
    const float* __restrict__ epsp, int epsIdx,
    int n0, int n1)
{
    int grp = threadIdx.x >> 5, lane = threadIdx.x & 31;
    int n = n0 + blockIdx.x * 8 + grp;
    if (n >= n1) return;
    int e0 = offs[n0];
    int k0 = offs[n], k1 = offs[n + 1];
    float s = 1.0f + epsp[epsIdx];
    ushort4 hv0 = *(const ushort4*)&h[(size_t)n * 128 + lane * 4];
    float m0 = s * bf2f(hv0.x), m1 = s * bf2f(hv0.y);
    float m2 = s * bf2f(hv0.z), m3 = s * bf2f(hv0.w);
    for (int k = k0; k < k1; ++k) {
        int2 mt = pmeta[k];
        float w = __int_as_float(mt.y);
        ushort4 ev = *(const ushort4*)&emsg[(size_t)(k - e0) * 128 + lane * 4];
        ushort4 hv = *(const ushort4*)&h[(size_t)mt.x * 128 + lane * 4];
        m0 += fmaxf(bf2f(hv.x) + bf2f(ev.x), 0.f) * w;
        m1 += fmaxf(bf2f(hv.y) + bf2f(ev.y), 0.f) * w;
        m2 += fmaxf(bf2f(hv.z) + bf2f(ev.z), 0.f) * w;
        m3 += fmaxf(bf2f(hv.w) + bf2f(ev.w), 0.f) * w;
    }
    ushort4 o;
    o.x = f2bfu(m0); o.y = f2bfu(m1); o.z = f2bfu(m2); o.w = f2bfu(m3);
    *(ushort4*)&a0[(size_t)n * 128 + lane * 4] = o;
}

// ---------------- gather (d=28) ----------------
__global__ __launch_bounds__(256) void k_gather28(
    const float* __restrict__ x, const unsigned short* __restrict__ xbf,
    const int* __restrict__ offs,
    const int2* __restrict__ pmeta, const unsigned short* __restrict__ emsg28,
    const float* __restrict__ eps1, float* __restrict__ u28, int N)
{
    int grp = threadIdx.x >> 5, lane = threadIdx.x & 31;
    int n = blockIdx.x * 8 + grp;
    if (n >= N || lane >= 28) return;
    float s = 1.0f + eps1[0];
    int k0 = offs[n], k1 = offs[n + 1];
    float m = 0.f;
    for (int k = k0; k < k1; ++k) {
        int2 mt = pmeta[k];
        float w = __int_as_float(mt.y);
        float e = bf2f(emsg28[(size_t)k * 28 + lane]);
        float xs = bf2f(xbf[(size_t)mt.x * 32 + lane]);
        m += fmaxf(xs + e, 0.f) * w;
    }
    u28[(size_t)n * 28 + lane] = fmaf(s, x[(size_t)n * 28 + lane], m);
}

// ---------------- fused node MLP (hidden): 1024 thr, 256-row tiles, 16 waves ----------------
__global__ __launch_bounds__(1024) void k_mlp(
    const unsigned short* __restrict__ src, const short* __restrict__ Wt1,
    const float* __restrict__ b1, const short* __restrict__ Wt2,
    const float* __restrict__ b2, unsigned short* __restrict__ dst,
    float* __restrict__ stats, int N)
{
    __shared__ short Bs1[128 * LDA];
    __shared__ short Bs2[128 * LDA];
    __shared__ short As[256 * LDA];
    __shared__ float sstat[256];
    int tid = threadIdx.x;
    for (int i = tid; i < 2048; i += 1024) {
        int n = (i * 8) >> 7, k = (i * 8) & 127;
        *(bf16x8*)&Bs1[n * LDA + k] = *(const bf16x8*)&Wt1[i * 8];
        *(bf16x8*)&Bs2[n * LDA + k] = *(const bf16x8*)&Wt2[i * 8];
    }
    if (tid < 256) sstat[tid] = 0.f;
    int w = tid >> 6, lane = tid & 63;   // w in [0,16): rows w*16..w*16+15
    int l15 = lane & 15, quad = lane >> 4;
    float b1r[8], b2r[8], lsum[8], lsq[8];
    #pragma unroll
    for (int nt = 0; nt < 8; ++nt) {
        int col = nt * 16 + l15;
        b1r[nt] = b1[col]; b2r[nt] = b2[col];
        lsum[nt] = 0.f; lsq[nt] = 0.f;
    }
    __syncthreads();

    int numTiles = (N + 255) >> 8;
    for (int tile = blockIdx.x; tile < numTiles; tile += gridDim.x) {
        int base = tile * 256;
        __syncthreads();
        #pragma unroll
        for (int kk = 0; kk < 4; ++kk) {
            int i = tid + kk * 1024;
            int row = (i * 8) >> 7, col = (i * 8) & 127;
            int rr = base + row;
            bf16x8 v;
            if (rr < N) v = *(const bf16x8*)&src[(size_t)rr * 128 + col];
            else        v = (bf16x8){0,0,0,0,0,0,0,0};
            *(bf16x8*)&As[row * LDA + col] = v;
        }
        __syncthreads();
        f32x4 acc[8];
        #pragma unroll
        for (int nt = 0; nt < 8; ++nt) acc[nt] = (f32x4){0.f, 0.f, 0.f, 0.f};
        #pragma unroll
        for (int kt = 0; kt < 4; ++kt) {
            bf16x8 af = *(bf16x8*)&As[(w * 16 + l15) * LDA + kt * 32 + quad * 8];
            #pragma unroll
            for (int nt = 0; nt < 8; ++nt) {
                bf16x8 bf = *(bf16x8*)&Bs1[(nt * 16 + l15) * LDA + kt * 32 + quad * 8];
                acc[nt] = __builtin_amdgcn_mfma_f32_16x16x32_bf16(af, bf, acc[nt], 0, 0, 0);
            }
        }
        #pragma unroll
        for (int nt = 0; nt < 8; ++nt) {
            int col = nt * 16 + l15;
            #pragma unroll
            for (int r = 0; r < 4; ++r)
                As[(w * 16 + quad * 4 + r) * LDA + col] = f2bf(fmaxf(acc[nt][r] + b1r[nt], 0.f));
        }
        __syncthreads();
        #pragma unroll
        for (int nt = 0; nt < 8; ++nt) acc[nt] = (f32x4){0.f, 0.f, 0.f, 0.f};
        #pragma unroll
        for (int kt = 0; kt < 4; ++kt) {
            bf16x8 af = *(bf16x8*)&As[(w * 16 + l15) * LDA + kt * 32 + quad * 8];
            #pragma unroll
            for (int nt = 0; nt < 8; ++nt) {
                bf16x8 bf = *(bf16x8*)&Bs2[(nt * 16 + l15) * LDA + kt * 32 + quad * 8];
                acc[nt] = __builtin_amdgcn_mfma_f32_16x16x32_bf16(af, bf, acc[nt], 0, 0, 0);
            }
        }
        int row0 = base + w * 16 + quad * 4;
        #pragma unroll
        for (int nt = 0; nt < 8; ++nt) {
            int col = nt * 16 + l15;
            #pragma unroll
            for (int r = 0; r < 4; ++r) {
                float z = acc[nt][r] + b2r[nt];
                if (row0 + r < N) { lsum[nt] += z; lsq[nt] = fmaf(z, z, lsq[nt]); }
                As[(w * 16 + quad * 4 + r) * LDA + col] = f2bf(z);
            }
        }
        __syncthreads();
        #pragma unroll
        for (int kk = 0; kk < 4; ++kk) {
            int i = tid + kk * 1024;
            int row = (i * 8) >> 7, col = (i * 8) & 127;
            int rr = base + row;
            if (rr < N)
                *(bf16x8*)&dst[(size_t)rr * 128 + col] = *(bf16x8*)&As[row * LDA + col];
        }
    }
    #pragma unroll
    for (int nt = 0; nt < 8; ++nt) {
        int col = nt * 16 + l15;
        atomicAdd(&sstat[col], lsum[nt]);
        atomicAdd(&sstat[128 + col], lsq[nt]);
    }
    __syncthreads();
    if (tid < 256) atomicAdd(&stats[tid], sstat[tid]);
}

// ---------------- fused layer-1 node MLP: 1024 thr, 256-row tiles ----------------
__global__ __launch_bounds__(1024) void k_mlp1(
    const float* __restrict__ u28, const short* __restrict__ Wt1p,
    const float* __restrict__ b1, const short* __restrict__ Wt2,
    const float* __restrict__ b2, unsigned short* __restrict__ dst,
    float* __restrict__ stats, int N)
{
    __shared__ short Bs1[128 * 40];
    __shared__ short Bs2[128 * LDA];
    __shared__ short As[256 * LDA];
    __shared__ short A28[256 * 40];
    __shared__ float sstat[256];
    int tid = threadIdx.x;
    for (int i = tid; i < 128 * 32; i += 1024) {
        int n = i >> 5, k = i & 31;
        Bs1[n * 40 + k] = Wt1p[i];
    }
    for (int i = tid; i < 2048; i += 1024) {
        int n = (i * 8) >> 7, k = (i * 8) & 127;
        *(bf16x8*)&Bs2[n * LDA + k] = *(const bf16x8*)&Wt2[i * 8];
    }
    {   // zero the K-pad columns (256 rows x 4 pad shorts)
        int r = tid >> 2, c = tid & 3;
        A28[r * 40 + 28 + c] = 0;
    }
    if (tid < 256) sstat[tid] = 0.f;
    int w = tid >> 6, lane = tid & 63;   // w in [0,16)
    int l15 = lane & 15, quad = lane >> 4;
    float b1r[8], b2r[8], lsum[8], lsq[8];
    #pragma unroll
    for (int nt = 0; nt < 8; ++nt) {
        int col = nt * 16 + l15;
        b1r[nt] = b1[col]; b2r[nt] = b2[col];
        lsum[nt] = 0.f; lsq[nt] = 0.f;
    }
    __syncthreads();

    int numTiles = (N + 255) >> 8;
    for (int tile = blockIdx.x; tile < numTiles; tile += gridDim.x) {
        int base = tile * 256;
        __syncthreads();
        for (int i = tid; i < 256 * 28; i += 1024) {
            int row = i / 28, col = i - row * 28;
            int rr = base + row;
            A28[row * 40 + col] = (rr < N) ? f2bf(u28[(size_t)rr * 28 + col]) : (short)0;
        }
        __syncthreads();
        f32x4 acc[8];
        #pragma unroll
        for (int nt = 0; nt < 8; ++nt) acc[nt] = (f32x4){0.f, 0.f, 0.f, 0.f};
        {
            bf16x8 af = *(bf16x8*)&A28[(w * 16 + l15) * 40 + quad * 8];
            #pragma unroll
            for (int nt = 0; nt < 8; ++nt) {
                bf16x8 bf = *(bf16x8*)&Bs1[(nt * 16 + l15) * 40 + quad * 8];
                acc[nt] = __builtin_amdgcn_mfma_f32_16x16x32_bf16(af, bf, acc[nt], 0, 0, 0);
            }
        }
        #pragma unroll
        for (int nt = 0; nt < 8; ++nt) {
            int col = nt * 16 + l15;
            #pragma unroll
            for (int r = 0; r < 4; ++r)
                As[(w * 16 + quad * 4 + r) * LDA + col] = f2bf(fmaxf(acc[nt][r] + b1r[nt], 0.f));
        }
        __syncthreads();
        #pragma unroll
        for (int nt = 0; nt < 8; ++nt) acc[nt] = (f32x4){0.f, 0.f, 0.f, 0.f};
        #pragma unroll
        for (int kt = 0; kt < 4; ++kt) {
            bf16x8 af = *(bf16x8*)&As[(w * 16 + l15) * LDA + kt * 32 + quad * 8];
            #pragma unroll
            for (int nt = 0; nt < 8; ++nt) {
                bf16x8 bf = *(bf16x8*)&Bs2[(nt * 16 + l15) * LDA + kt * 32 + quad * 8];
                acc[nt] = __builtin_amdgcn_mfma_f32_16x16x32_bf16(af, bf, acc[nt], 0, 0, 0);
            }
        }
        int row0 = base + w * 16 + quad * 4;
        #pragma unroll
        for (int nt = 0; nt < 8; ++nt) {
            int col = nt * 16 + l15;
            #pragma unroll
            for (int r = 0; r < 4; ++r) {
                float z = acc[nt][r] + b2r[nt];
                if (row0 + r < N) { lsum[nt] += z; lsq[nt] = fmaf(z, z, lsq[nt]); }
                As[(w * 16 + quad * 4 + r) * LDA + col] = f2bf(z);
            }
        }
        __syncthreads();
        #pragma unroll
        for (int kk = 0; kk < 4; ++kk) {
            int i = tid + kk * 1024;
            int row = (i * 8) >> 7, col = (i * 8) & 127;
            int rr = base + row;
            if (rr < N)
                *(bf16x8*)&dst[(size_t)rr * 128 + col] = *(bf16x8*)&As[row * LDA + col];
        }
    }
    #pragma unroll
    for (int nt = 0; nt < 8; ++nt) {
        int col = nt * 16 + l15;
        atomicAdd(&sstat[col], lsum[nt]);
        atomicAdd(&sstat[128 + col], lsq[nt]);
    }
    __syncthreads();
    if (tid < 256) atomicAdd(&stats[tid], sstat[tid]);
}

// ---------------- stats -> scale/shift ----------------
__global__ __launch_bounds__(128) void k_stats(
    const float* __restrict__ stats, const float* __restrict__ g,
    const float* __restrict__ b, float* __restrict__ ss, float invN)
{
    int j = threadIdx.x;
    float mu  = stats[j] * invN;
    float var = fmaf(stats[128 + j], invN, -mu * mu);
    float sc  = rsqrtf(fmaxf(var, 0.f) + BNEPS) * g[j];
    ss[j] = sc;
    ss[128 + j] = fmaf(-mu, sc, b[j]);
}

// ---------------- BN-apply+relu(+residual), 16B lanes ----------------
__global__ __launch_bounds__(256) void k_bn(
    const unsigned short* __restrict__ z, const float* __restrict__ ss,
    unsigned short* __restrict__ h, int residual, int N)
{
    int idx8 = blockIdx.x * 256 + threadIdx.x;
    int stride = gridDim.x * 256;
    int c0 = (idx8 & 15) * 8;
    float scl[8], sht[8];
    #pragma unroll
    for (int r = 0; r < 8; ++r) { scl[r] = ss[c0 + r]; sht[r] = ss[128 + c0 + r]; }
    int total8 = N * 16;
    for (; idx8 < total8; idx8 += stride) {
        int n = idx8 >> 4;
        u16x8 z8 = *(const u16x8*)&z[(size_t)n * 128 + c0];
        float hn[8];
        #pragma unroll
        for (int r = 0; r < 8; ++r)
            hn[r] = fmaxf(fmaf(bf2f(z8[r]), scl[r], sht[r]), 0.f);
        if (residual) {
            u16x8 h8 = *(const u16x8*)&h[(size_t)n * 128 + c0];
            #pragma unroll
            for (int r = 0; r < 8; ++r) hn[r] += bf2f(h8[r]);
        }
        u16x8 o;
        #pragma unroll
        for (int r = 0; r < 8; ++r) o[r] = f2bfu(hn[r]);
        *(u16x8*)&h[(size_t)n * 128 + c0] = o;
    }
}

// ---------------- pool with fused last-layer BN+residual ----------------
__global__ __launch_bounds__(256) void k_poolbn(
    const unsigned short* __restrict__ z, const unsigned short* __restrict__ hprev,
    const float* __restrict__ ss, const int* __restrict__ offs2,
    const int* __restrict__ perm2, float* __restrict__ out, int S)
{
    int w = threadIdx.x >> 6, lane = threadIdx.x & 63;
    int s = blockIdx.x * 4 + w;
    if (s >= S) return;
    int c0 = lane * 2;
    float scl0 = ss[c0], scl1 = ss[c0 + 1];
    float sht0 = ss[128 + c0], sht1 = ss[128 + c0 + 1];
    int k0 = offs2[s], k1 = offs2[s + 1];
    float a0 = 0.f, a1 = 0.f;
    for (int k = k0; k < k1; ++k) {
        int n = perm2[k];
        ushort2 zv = *(const ushort2*)&z[(size_t)n * 128 + c0];
        ushort2 hv = *(const ushort2*)&hprev[(size_t)n * 128 + c0];
        a0 += fmaxf(fmaf(bf2f(zv.x), scl0, sht0), 0.f) + bf2f(hv.x);
        a1 += fmaxf(fmaf(bf2f(zv.y), scl1, sht1), 0.f) + bf2f(hv.y);
    }
    *(float2*)&out[(size_t)s * 128 + c0] = make_float2(a0, a1);
}

extern "C" void kernel_launch(void* const* d_in, const int* in_sizes, int n_in,
                              void* d_out, int out_size, void* d_ws, size_t ws_size,
                              hipStream_t stream) {
    const float* x    = (const float*)d_in[0];
    const int*   ei   = (const int*)d_in[1];
    const float* ea   = (const float*)d_in[2];
    const float* ew   = (const float*)d_in[3];
    const float* mask = (const float*)d_in[4];
    const int*   s2n  = (const int*)d_in[5];
    const float* be1W1 = (const float*)d_in[6];
    const float* be1b1 = (const float*)d_in[7];
    const float* be1W2 = (const float*)d_in[8];
    const float* be1b2 = (const float*)d_in[9];
    const float* m1W1  = (const float*)d_in[10];
    const float* m1b1  = (const float*)d_in[11];
    const float* m1W2  = (const float*)d_in[12];
    const float* m1b2  = (const float*)d_in[13];
    const float* bn1g  = (const float*)d_in[14];
    const float* bn1b  = (const float*)d_in[15];
    const float* eps1  = (const float*)d_in[16];
    const float* beW1  = (const float*)d_in[17];
    const float* beb1  = (const float*)d_in[18];
    const float* beW2  = (const float*)d_in[19];
    const float* beb2  = (const float*)d_in[20];
    const float* mW1   = (const float*)d_in[21];
    const float* mb1   = (const float*)d_in[22];
    const float* mW2   = (const float*)d_in[23];
    const float* mb2   = (const float*)d_in[24];
    const float* bng   = (const float*)d_in[25];
    const float* bnb   = (const float*)d_in[26];
    const float* epsL  = (const float*)d_in[27];

    const int N = in_sizes[0] / 28;
    const int E = in_sizes[1] / 2;
    const int S = out_size / 128;
    const float invN = 1.0f / (float)N;
    const int NS = N / 2;
    const int EMC = E / 2 + 8192;

    auto al16 = [](size_t v) { return (v + 15) & ~(size_t)15; };
    char* ws = (char*)d_ws;
    size_t offH      = 0;
    size_t offA0     = al16(offH + (size_t)N * 256);
    size_t offEm     = al16(offA0 + (size_t)N * 256);
    size_t emBytes   = (size_t)EMC * 256;
    if ((size_t)E * 56 > emBytes) emBytes = (size_t)E * 56;
    size_t offStats  = al16(offEm + emBytes);
    size_t offSS     = al16(offStats + 4096);
    size_t offWts    = al16(offSS + 1024);
    size_t offCounts = al16(offWts + 10 * 16384 * 2 + 4096 * 2 + 1024 * 2);
    size_t offOffs   = al16(offCounts + (size_t)N * 4);
    size_t offCursor = al16(offOffs + (size_t)(N + 1) * 4);
    size_t offPmeta  = al16(offCursor + (size_t)N * 4);
    size_t offPea    = al16(offPmeta + (size_t)E * 8);
    size_t offBsum   = al16(offPea + (size_t)E * 16);
    size_t offCnt2   = al16(offBsum + SCAN_NB * 4);
    size_t offOffs2  = al16(offCnt2 + (size_t)S * 4);
    size_t offCur2   = al16(offOffs2 + (size_t)(S + 1) * 4);
    size_t offPerm2  = al16(offCur2 + (size_t)S * 4);
    size_t need      = offPerm2 + (size_t)N * 4;
    if (ws_size < need) return;

    unsigned short* h    = (unsigned short*)(ws + offH);
    unsigned short* a0   = (unsigned short*)(ws + offA0);
    unsigned short* emsg = (unsigned short*)(ws + offEm);
    float* u28    = (float*)(ws + offA0);
    unsigned short* xbf = (unsigned short*)(ws + offA0 + 26214400);
    float* stats  = (float*)(ws + offStats);
    float* ssbuf  = (float*)(ws + offSS);
    short* wts    = (short*)(ws + offWts);
    short* w1p    = wts + 10 * 16384;
    short* w2p28  = w1p + 4096;
    int*   counts = (int*)(ws + offCounts);
    int*   offs   = (int*)(ws + offOffs);
    int*   cursor = (int*)(ws + offCursor);
    int2*  pmeta  = (int2*)(ws + offPmeta);
    float4* pea4  = (float4*)(ws + offPea);
    int*   bsum   = (int*)(ws + offBsum);
    int*   cnt2   = (int*)(ws + offCnt2);
    int*   offs2  = (int*)(ws + offOffs2);
    int*   cur2   = (int*)(ws + offCur2);
    int*   perm2  = (int*)(ws + offPerm2);
    const float4* ea4 = (const float4*)ea;

    hipMemsetAsync(stats, 0, 4 * 256 * sizeof(float), stream);
    hipMemsetAsync(counts, 0, (size_t)N * sizeof(int), stream);
    hipMemsetAsync(cnt2, 0, (size_t)S * sizeof(int), stream);

    k_prep<<<40, 256, 0, stream>>>(m1W2, beW2, mW1, mW2, wts);
    k_prep1<<<1, 256, 0, stream>>>(m1W1, w1p);
    k_prep28<<<1, 256, 0, stream>>>(be1W2, w2p28);
    k_prepx<<<512, 256, 0, stream>>>(x, xbf, N);

    // ---- edge CSR (dst-sorted; attrs pre-permuted) ----
    const int seg = (N + SCAN_NB - 1) / SCAN_NB;
    k_count<<<1024, 256, 0, stream>>>(ei, counts, E);
    k_scanA<<<SCAN_NB, 256, 0, stream>>>(counts, bsum, N, seg);
    k_scanB<<<1, 256, 0, stream>>>(bsum, SCAN_NB, offs, N);
    k_scanC<<<SCAN_NB, 256, 0, stream>>>(counts, bsum, offs, cursor, N, seg);
    k_scatter<<<1024, 256, 0, stream>>>(ei, ew, ea4, cursor, pmeta, pea4, E);

    // ---- segment CSR ----
    const int seg2 = (S + SCAN_NB - 1) / SCAN_NB;
    k_count2<<<512, 256, 0, stream>>>(s2n, mask, cnt2, N);
    k_scanA<<<SCAN_NB, 256, 0, stream>>>(cnt2, bsum, S, seg2);
    k_scanB<<<1, 256, 0, stream>>>(bsum, SCAN_NB, offs2, S);
    k_scanC<<<SCAN_NB, 256, 0, stream>>>(cnt2, bsum, offs2, cur2, S, seg2);
    k_scatter2<<<512, 256, 0, stream>>>(s2n, mask, cur2, perm2, N);

    auto wt_be = [&](int l) { return wts + (size_t)(1 + 3 * l + 0) * 16384; };
    auto wt_m1 = [&](int l) { return wts + (size_t)(1 + 3 * l + 1) * 16384; };
    auto wt_m2 = [&](int l) { return wts + (size_t)(1 + 3 * l + 2) * 16384; };

    // ---- layer 1 (28 -> 128) ----
    k_emsg28_mm<<<2048, 256, 0, stream>>>(pea4, be1W1, be1b1, w2p28, be1b2, emsg, E);
    k_gather28<<<(N + 7) / 8, 256, 0, stream>>>(x, xbf, offs, pmeta, emsg, eps1, u28, N);
    k_mlp1<<<256, 1024, 0, stream>>>(u28, w1p, m1b1, wts /*m1W2t*/, m1b2, h, stats, N);
    k_stats<<<1, 128, 0, stream>>>(stats, bn1g, bn1b, ssbuf, invN);
    k_bn<<<2048, 256, 0, stream>>>(h, ssbuf, h, 0, N);

    // ---- layers 2..4 (node-range chunks) ----
    for (int l = 0; l < 3; ++l) {
        for (int c = 0; c < 2; ++c) {
            int n0 = (c == 0) ? 0 : NS;
            int n1 = (c == 0) ? NS : N;
            k_emsg<<<2048, 512, 0, stream>>>(pea4,
                beW1 + (size_t)l * 512, beb1 + (size_t)l * 128,
                wt_be(l), beb2 + (size_t)l * 128, emsg, offs, n0, n1);
            k_gather<<<(n1 - n0 + 7) / 8, 256, 0, stream>>>(h, offs, pmeta, emsg, a0,
                epsL, l, n0, n1);
        }
        k_mlp<<<256, 1024, 0, stream>>>(a0, wt_m1(l), mb1 + (size_t)l * 128,
                                        wt_m2(l), mb2 + (size_t)l * 128, a0,
                                        stats + 256 * (l + 1), N);
        k_stats<<<1, 128, 0, stream>>>(stats + 256 * (l + 1),
            bng + (size_t)l * 128, bnb + (size_t)l * 128, ssbuf, invN);
        if (l < 2) {
            k_bn<<<2048, 256, 0, stream>>>(a0, ssbuf, h, 1, N);
        }
    }

    // ---- pool with fused layer-4 BN+residual ----
    k_poolbn<<<(S + 3) / 4, 256, 0, stream>>>(a0, h, ssbuf, offs2, perm2,
                                              (float*)d_out, S);
}

// Round 13
// 1035.948 us; speedup vs baseline: 1.0576x; 1.0576x over previous
//
#include <hip/hip_runtime.h>
#include <hip/hip_bf16.h>

// ZINC GINE inner, round 13: r11 config + register-cached B fragments in
// k_mlp/k_mlp1 (r11/r12 were LDS-BW-bound re-reading weight fragments:
// 36 ds_read_b128 per GEMM per wave -> now 4; B1+B2 slices live in 128 VGPRs).
// r12 lesson: occupancy wasn't the constraint; LDS traffic was.

#define BNEPS 1e-5f
#define LDA 136   // 128 + 8 shorts pad
#define SCAN_NB 240

typedef __attribute__((ext_vector_type(8))) short bf16x8;
typedef __attribute__((ext_vector_type(8))) unsigned short u16x8;
typedef __attribute__((ext_vector_type(4))) float f32x4;

__device__ inline short f2bf(float f) {
    __hip_bfloat16 h = __float2bfloat16(f);
    return *reinterpret_cast<short*>(&h);
}
__device__ inline unsigned short f2bfu(float f) {
    __hip_bfloat16 h = __float2bfloat16(f);
    return *reinterpret_cast<unsigned short*>(&h);
}
__device__ inline float bf2f(unsigned short u) {
    union { unsigned int i; float f; } v; v.i = ((unsigned int)u) << 16; return v.f;
}

// ---------------- prep: transpose 10 f32 [128,128] weights -> bf16 W^T ----------------
__global__ __launch_bounds__(256) void k_prep(
    const float* __restrict__ m1W2, const float* __restrict__ beW2,
    const float* __restrict__ mW1, const float* __restrict__ mW2,
    short* __restrict__ out)
{
    __shared__ float tileS[64][65];
    int b = blockIdx.x, mat = b >> 2, t = b & 3;
    const float* Wsrc;
    if (mat == 0) Wsrc = m1W2;
    else {
        int l = (mat - 1) / 3, which = (mat - 1) % 3;
        Wsrc = (which == 0) ? beW2 + (size_t)l * 16384
             : (which == 1) ? mW1 + (size_t)l * 16384
             :                mW2 + (size_t)l * 16384;
    }
    short* dst = out + (size_t)mat * 16384;
    int tr = (t >> 1) * 64, tc = (t & 1) * 64;
    for (int i = threadIdx.x; i < 4096; i += 256) {
        int r = i >> 6, c = i & 63;
        tileS[r][c] = Wsrc[(size_t)(tr + r) * 128 + (tc + c)];
    }
    __syncthreads();
    for (int i = threadIdx.x; i < 4096; i += 256) {
        int n = i >> 6, k = i & 63;
        dst[(size_t)(tc + n) * 128 + (tr + k)] = f2bf(tileS[k][n]);
    }
}

// ---------------- prep: layer-1 W1 [28,128] -> bf16 W^T padded K=32 ----------------
__global__ __launch_bounds__(256) void k_prep1(
    const float* __restrict__ W1, short* __restrict__ out)
{
    for (int i = threadIdx.x; i < 128 * 32; i += 256) {
        int n = i >> 5, k = i & 31;
        out[i] = (k < 28) ? f2bf(W1[(size_t)k * 128 + n]) : (short)0;
    }
}

// ---------------- prep: layer-1 edge W2 [28,28] -> bf16 W^T padded [32][32] ----------------
__global__ __launch_bounds__(256) void k_prep28(
    const float* __restrict__ W2, short* __restrict__ out)
{
    for (int i = threadIdx.x; i < 32 * 32; i += 256) {
        int n = i >> 5, k = i & 31;
        out[i] = (n < 28 && k < 28) ? f2bf(W2[(size_t)k * 28 + n]) : (short)0;
    }
}

// ---------------- prep: x [N,28] f32 -> x_bf [N,32] bf16 ----------------
__global__ __launch_bounds__(256) void k_prepx(
    const float* __restrict__ x, unsigned short* __restrict__ xbf, int N)
{
    int total = N * 32;
    for (int i = blockIdx.x * 256 + threadIdx.x; i < total; i += gridDim.x * 256) {
        int n = i >> 5, c = i & 31;
        xbf[i] = (c < 28) ? f2bfu(x[(size_t)n * 28 + c]) : (unsigned short)0;
    }
}

// ---------------- CSR build ----------------
__global__ __launch_bounds__(256) void k_count(
    const int* __restrict__ ei, int* __restrict__ counts, int E)
{
    for (int e = blockIdx.x * 256 + threadIdx.x; e < E; e += gridDim.x * 256)
        atomicAdd(&counts[ei[E + e]], 1);
}

__global__ __launch_bounds__(256) void k_count2(
    const int* __restrict__ s2n, const float* __restrict__ mask,
    int* __restrict__ counts2, int N)
{
    for (int n = blockIdx.x * 256 + threadIdx.x; n < N; n += gridDim.x * 256)
        if (mask[n] != 0.f) atomicAdd(&counts2[s2n[n]], 1);
}

__global__ __launch_bounds__(256) void k_scanA(
    const int* __restrict__ counts, int* __restrict__ bsum, int N, int seg)
{
    __shared__ int red[256];
    int b = blockIdx.x;
    int lo = b * seg, hi = min(lo + seg, N);
    int s = 0;
    for (int i = lo + threadIdx.x; i < hi; i += 256) s += counts[i];
    red[threadIdx.x] = s;
    __syncthreads();
    for (int d = 128; d > 0; d >>= 1) {
        if (threadIdx.x < d) red[threadIdx.x] += red[threadIdx.x + d];
        __syncthreads();
    }
    if (threadIdx.x == 0) bsum[b] = red[0];
}

__global__ __launch_bounds__(256) void k_scanB(
    int* __restrict__ bsum, int nb, int* __restrict__ offs, int N)
{
    __shared__ int sh[256];
    int v = (threadIdx.x < nb) ? bsum[threadIdx.x] : 0;
    sh[threadIdx.x] = v;
    __syncthreads();
    for (int d = 1; d < 256; d <<= 1) {
        int t = (threadIdx.x >= d) ? sh[threadIdx.x - d] : 0;
        __syncthreads();
        sh[threadIdx.x] += t;
        __syncthreads();
    }
    if (threadIdx.x < nb) bsum[threadIdx.x] = sh[threadIdx.x] - v;
    if (threadIdx.x == 0) offs[N] = sh[255];
}

__global__ __launch_bounds__(256) void k_scanC(
    const int* __restrict__ counts, const int* __restrict__ bsum,
    int* __restrict__ offs, int* __restrict__ cursor, int N, int seg)
{
    __shared__ int sh[256];
    int b = blockIdx.x;
    int lo = b * seg, hi = min(lo + seg, N);
    int base = bsum[b];
    for (int t0 = lo; t0 < hi; t0 += 256) {
        int i = t0 + threadIdx.x;
        int v = (i < hi) ? counts[i] : 0;
        sh[threadIdx.x] = v;
        __syncthreads();
        for (int d = 1; d < 256; d <<= 1) {
            int t = (threadIdx.x >= d) ? sh[threadIdx.x - d] : 0;
            __syncthreads();
            sh[threadIdx.x] += t;
            __syncthreads();
        }
        int excl = base + sh[threadIdx.x] - v;
        if (i < hi) { offs[i] = excl; cursor[i] = excl; }
        int tileTotal = sh[255];
        __syncthreads();
        base += tileTotal;
    }
}

__global__ __launch_bounds__(256) void k_scatter(
    const int* __restrict__ ei, const float* __restrict__ ew,
    const float4* __restrict__ ea4,
    int* __restrict__ cursor, int2* __restrict__ pmeta,
    float4* __restrict__ pea4, int E)
{
    for (int e = blockIdx.x * 256 + threadIdx.x; e < E; e += gridDim.x * 256) {
        int d = ei[E + e];
        int pos = atomicAdd(&cursor[d], 1);
        pmeta[pos] = make_int2(ei[e], __float_as_int(ew[e]));
        pea4[pos] = ea4[e];
    }
}

__global__ __launch_bounds__(256) void k_scatter2(
    const int* __restrict__ s2n, const float* __restrict__ mask,
    int* __restrict__ cursor2, int* __restrict__ perm2, int N)
{
    for (int n = blockIdx.x * 256 + threadIdx.x; n < N; n += gridDim.x * 256)
        if (mask[n] != 0.f) {
            int pos = atomicAdd(&cursor2[s2n[n]], 1);
            perm2[pos] = n;
        }
}

// ---------------- hidden edge GEMM over node-chunk edge range (r11 version) ----------------
__global__ __launch_bounds__(256) void k_emsg(
    const float4* __restrict__ pea4,
    const float* __restrict__ W1, const float* __restrict__ b1,
    const short* __restrict__ W2t, const float* __restrict__ b2,
    unsigned short* __restrict__ emsg, const int* __restrict__ offs,
    int n0, int n1)
{
    __shared__ short Bs[128 * LDA];
    __shared__ short As[64 * LDA];
    __shared__ float eas[64][4];
    int e0 = offs[n0], e1 = offs[n1];
    int tid = threadIdx.x;
    for (int i = tid; i < 2048; i += 256) {
        int n = (i * 8) >> 7, k = (i * 8) & 127;
        *(bf16x8*)&Bs[n * LDA + k] = *(const bf16x8*)&W2t[i * 8];
    }
    int j = tid & 127, half = tid >> 7;
    float w10 = W1[j], w11 = W1[128 + j], w12 = W1[256 + j], w13 = W1[384 + j];
    float b1j = b1[j];
    int w = tid >> 6, lane = tid & 63;
    int l15 = lane & 15, quad = lane >> 4;
    __syncthreads();

    int numTiles = (e1 - e0 + 63) >> 6;
    for (int tile = blockIdx.x; tile < numTiles; tile += gridDim.x) {
        int base = e0 + tile * 64;
        __syncthreads();
        if (tid < 64) {
            int k = base + tid;
            float4 a = make_float4(0.f, 0.f, 0.f, 0.f);
            if (k < e1) a = pea4[k];
            eas[tid][0] = a.x; eas[tid][1] = a.y; eas[tid][2] = a.z; eas[tid][3] = a.w;
        }
        __syncthreads();
        #pragma unroll
        for (int q = 0; q < 32; ++q) {
            int e = half * 32 + q;
            float t = fmaf(eas[e][0], w10, fmaf(eas[e][1], w11,
                      fmaf(eas[e][2], w12, fmaf(eas[e][3], w13, b1j))));
            As[e * LDA + j] = f2bf(fmaxf(t, 0.f));
        }
        __syncthreads();
        f32x4 acc[8];
        #pragma unroll
        for (int nt = 0; nt < 8; ++nt) acc[nt] = (f32x4){0.f, 0.f, 0.f, 0.f};
        #pragma unroll
        for (int kt = 0; kt < 4; ++kt) {
            bf16x8 af = *(bf16x8*)&As[(w * 16 + l15) * LDA + kt * 32 + quad * 8];
            #pragma unroll
            for (int nt = 0; nt < 8; ++nt) {
                bf16x8 bf = *(bf16x8*)&Bs[(nt * 16 + l15) * LDA + kt * 32 + quad * 8];
                acc[nt] = __builtin_amdgcn_mfma_f32_16x16x32_bf16(af, bf, acc[nt], 0, 0, 0);
            }
        }
        #pragma unroll
        for (int nt = 0; nt < 8; ++nt) {
            int col = nt * 16 + l15;
            float b2c = b2[col];
            #pragma unroll
            for (int r = 0; r < 4; ++r) {
                int row = w * 16 + quad * 4 + r;
                As[row * LDA + col] = f2bf(acc[nt][r] + b2c);
            }
        }
        __syncthreads();
        #pragma unroll
        for (int kk = 0; kk < 4; ++kk) {
            int i = tid + kk * 256;
            int row = (i * 8) >> 7, col = (i * 8) & 127;
            int gr = base + row;
            if (gr < e1)
                *(bf16x8*)&emsg[(size_t)(gr - e0) * 128 + col] = *(bf16x8*)&As[row * LDA + col];
        }
    }
}

// ---------------- layer-1 edge MLP via MFMA ----------------
__global__ __launch_bounds__(256) void k_emsg28_mm(
    const float4* __restrict__ pea4,
    const float* __restrict__ W1, const float* __restrict__ b1,
    const short* __restrict__ W2t28,
    const float* __restrict__ b2,
    unsigned short* __restrict__ emsg28, int E)
{
    __shared__ short Bs[32 * 40];
    __shared__ short As[64 * 40];
    __shared__ float eas[64][4];
    __shared__ float b2s[32];
    int tid = threadIdx.x;
    for (int i = tid; i < 32 * 32; i += 256) {
        int n = i >> 5, k = i & 31;
        Bs[n * 40 + k] = W2t28[i];
    }
    if (tid < 32) b2s[tid] = (tid < 28) ? b2[tid] : 0.f;
    int j = tid & 31, sub = tid >> 5;
    float w10 = 0.f, w11 = 0.f, w12 = 0.f, w13 = 0.f, b1j = 0.f;
    if (j < 28) { w10 = W1[j]; w11 = W1[28 + j]; w12 = W1[56 + j]; w13 = W1[84 + j]; b1j = b1[j]; }
    int w = tid >> 6, lane = tid & 63;
    int l15 = lane & 15, quad = lane >> 4;
    __syncthreads();

    int numTiles = (E + 63) >> 6;
    for (int tile = blockIdx.x; tile < numTiles; tile += gridDim.x) {
        int base = tile * 64;
        __syncthreads();
        if (tid < 64) {
            int k = base + tid;
            float4 a = (k < E) ? pea4[k] : make_float4(0.f, 0.f, 0.f, 0.f);
            eas[tid][0] = a.x; eas[tid][1] = a.y; eas[tid][2] = a.z; eas[tid][3] = a.w;
        }
        __syncthreads();
        #pragma unroll
        for (int q = 0; q < 8; ++q) {
            int e = q * 8 + sub;
            float t = fmaf(eas[e][0], w10, fmaf(eas[e][1], w11,
                      fmaf(eas[e][2], w12, fmaf(eas[e][3], w13, b1j))));
            As[e * 40 + j] = (j < 28) ? f2bf(fmaxf(t, 0.f)) : (short)0;
        }
        __syncthreads();
        f32x4 acc[2];
        acc[0] = (f32x4){0.f, 0.f, 0.f, 0.f};
        acc[1] = (f32x4){0.f, 0.f, 0.f, 0.f};
        bf16x8 af = *(bf16x8*)&As[(w * 16 + l15) * 40 + quad * 8];
        #pragma unroll
        for (int nt = 0; nt < 2; ++nt) {
            bf16x8 bf = *(bf16x8*)&Bs[(nt * 16 + l15) * 40 + quad * 8];
            acc[nt] = __builtin_amdgcn_mfma_f32_16x16x32_bf16(af, bf, acc[nt], 0, 0, 0);
        }
        __syncthreads();
        #pragma unroll
        for (int nt = 0; nt < 2; ++nt) {
            int col = nt * 16 + l15;
            float bb = b2s[col];
            #pragma unroll
            for (int r = 0; r < 4; ++r)
                As[(w * 16 + quad * 4 + r) * 40 + col] = f2bf(acc[nt][r] + bb);
        }
        __syncthreads();
        for (int i = tid; i < 64 * 28; i += 256) {
            int row = i / 28, col = i - row * 28;
            int gr = base + row;
            if (gr < E) emsg28[(size_t)gr * 28 + col] = As[row * 40 + col];
        }
    }
}

// ---------------- gather node-chunk [n0,n1) ----------------
__global__ __launch_bounds__(256) void k_gather(
    const unsigned short* __restrict__ h, const int* __restrict__ offs,
    const int2* __restrict__ pmeta, const unsigned short* __restrict__ emsg,
    unsigned short* __restrict__ a0,
    const float* __restrict__ epsp, int epsIdx,
    int n0, int n1)
{
    int grp = threadIdx.x >> 5, lane = threadIdx.x & 31;
    int n = n0 + blockIdx.x * 8 + grp;
    if (n >= n1) return;
    int e0 = offs[n0];
    int k0 = offs[n], k1 = offs[n + 1];
    float s = 1.0f + epsp[epsIdx];
    ushort4 hv0 = *(const ushort4*)&h[(size_t)n * 128 + lane * 4];
    float m0 = s * bf2f(hv0.x), m1 = s * bf2f(hv0.y);
    float m2 = s * bf2f(hv0.z), m3 = s * bf2f(hv0.w);
    for (int k = k0; k < k1; ++k) {
        int2 mt = pmeta[k];
        float w = __int_as_float(mt.y);
        ushort4 ev = *(const ushort4*)&emsg[(size_t)(k - e0) * 128 + lane * 4];
        ushort4 hv = *(const ushort4*)&h[(size_t)mt.x * 128 + lane * 4];
        m0 += fmaxf(bf2f(hv.x) + bf2f(ev.x), 0.f) * w;
        m1 += fmaxf(bf2f(hv.y) + bf2f(ev.y), 0.f) * w;
        m2 += fmaxf(bf2f(hv.z) + bf2f(ev.z), 0.f) * w;
        m3 += fmaxf(bf2f(hv.w) + bf2f(ev.w), 0.f) * w;
    }
    ushort4 o;
    o.x = f2bfu(m0); o.y = f2bfu(m1); o.z = f2bfu(m2); o.w = f2bfu(m3);
    *(ushort4*)&a0[(size_t)n * 128 + lane * 4] = o;
}

// ---------------- gather (d=28) ----------------
__global__ __launch_bounds__(256) void k_gather28(
    const float* __restrict__ x, const unsigned short* __restrict__ xbf,
    const int* __restrict__ offs,
    const int2* __restrict__ pmeta, const unsigned short* __restrict__ emsg28,
    const float* __restrict__ eps1, float* __restrict__ u28, int N)
{
    int grp = threadIdx.x >> 5, lane = threadIdx.x & 31;
    int n = blockIdx.x * 8 + grp;
    if (n >= N || lane >= 28) return;
    float s = 1.0f + eps1[0];
    int k0 = offs[n], k1 = offs[n + 1];
    float m = 0.f;
    for (int k = k0; k < k1; ++k) {
        int2 mt = pmeta[k];
        float w = __int_as_float(mt.y);
        float e = bf2f(emsg28[(size_t)k * 28 + lane]);
        float xs = bf2f(xbf[(size_t)mt.x * 32 + lane]);
        m += fmaxf(xs + e, 0.f) * w;
    }
    u28[(size_t)n * 28 + lane] = fmaf(s, x[(size_t)n * 28 + lane], m);
}

// ---------------- fused node MLP (hidden): 512 thr, 128-row tiles, reg-cached B ----------------
// wave w: col-group cg = w>>2 (64 cols), row base (w&3)*32 (two 16-row groups).
__global__ __launch_bounds__(512) void k_mlp(
    const unsigned short* __restrict__ src, const short* __restrict__ Wt1,
    const float* __restrict__ b1, const short* __restrict__ Wt2,
    const float* __restrict__ b2, unsigned short* __restrict__ dst,
    float* __restrict__ stats, int N)
{
    __shared__ short Bs1[128 * LDA];
    __shared__ short Bs2[128 * LDA];
    __shared__ short As[128 * LDA];
    __shared__ float sstat[256];
    int tid = threadIdx.x;
    for (int i = tid; i < 2048; i += 512) {
        int n = (i * 8) >> 7, k = (i * 8) & 127;
        *(bf16x8*)&Bs1[n * LDA + k] = *(const bf16x8*)&Wt1[i * 8];
        *(bf16x8*)&Bs2[n * LDA + k] = *(const bf16x8*)&Wt2[i * 8];
    }
    if (tid < 256) sstat[tid] = 0.f;
    int w = tid >> 6, lane = tid & 63;
    int l15 = lane & 15, quad = lane >> 4;
    int cg = w >> 2;                 // 0/1 : cols cg*64 .. +63
    int rb = (w & 3) * 32;           // rows rb .. rb+31 (two 16-row MFMA groups)
    __syncthreads();

    // register-cache this wave's B fragments for both GEMMs (32 x bf16x8)
    bf16x8 B1f[4][4], B2f[4][4];
    float b1r[4], b2r[4];
    #pragma unroll
    for (int nt = 0; nt < 4; ++nt) {
        int col = cg * 64 + nt * 16 + l15;
        b1r[nt] = b1[col]; b2r[nt] = b2[col];
        #pragma unroll
        for (int kt = 0; kt < 4; ++kt) {
            B1f[nt][kt] = *(bf16x8*)&Bs1[col * LDA + kt * 32 + quad * 8];
            B2f[nt][kt] = *(bf16x8*)&Bs2[col * LDA + kt * 32 + quad * 8];
        }
    }
    float lsum[2][4], lsq[2][4];
    #pragma unroll
    for (int rg = 0; rg < 2; ++rg)
        #pragma unroll
        for (int nt = 0; nt < 4; ++nt) { lsum[rg][nt] = 0.f; lsq[rg][nt] = 0.f; }

    int numTiles = (N + 127) >> 7;
    for (int tile = blockIdx.x; tile < numTiles; tile += gridDim.x) {
        int base = tile * 128;
        __syncthreads();   // As reuse guard
        #pragma unroll
        for (int kk = 0; kk < 4; ++kk) {
            int i = tid + kk * 512;
            int row = (i * 8) >> 7, col = (i * 8) & 127;
            int rr = base + row;
            bf16x8 v;
            if (rr < N) v = *(const bf16x8*)&src[(size_t)rr * 128 + col];
            else        v = (bf16x8){0,0,0,0,0,0,0,0};
            *(bf16x8*)&As[row * LDA + col] = v;
        }
        __syncthreads();
        // GEMM1
        f32x4 acc[2][4];
        #pragma unroll
        for (int rg = 0; rg < 2; ++rg)
            #pragma unroll
            for (int nt = 0; nt < 4; ++nt) acc[rg][nt] = (f32x4){0.f, 0.f, 0.f, 0.f};
        #pragma unroll
        for (int rg = 0; rg < 2; ++rg) {
            #pragma unroll
            for (int kt = 0; kt < 4; ++kt) {
                bf16x8 af = *(bf16x8*)&As[(rb + rg * 16 + l15) * LDA + kt * 32 + quad * 8];
                #pragma unroll
                for (int nt = 0; nt < 4; ++nt)
                    acc[rg][nt] = __builtin_amdgcn_mfma_f32_16x16x32_bf16(af, B1f[nt][kt], acc[rg][nt], 0, 0, 0);
            }
        }
        __syncthreads();   // all GEMM1 A-reads done before t overwrites As
        #pragma unroll
        for (int rg = 0; rg < 2; ++rg)
            #pragma unroll
            for (int nt = 0; nt < 4; ++nt) {
                int col = cg * 64 + nt * 16 + l15;
                #pragma unroll
                for (int r = 0; r < 4; ++r)
                    As[(rb + rg * 16 + quad * 4 + r) * LDA + col] =
                        f2bf(fmaxf(acc[rg][nt][r] + b1r[nt], 0.f));
            }
        __syncthreads();
        // GEMM2
        #pragma unroll
        for (int rg = 0; rg < 2; ++rg)
            #pragma unroll
            for (int nt = 0; nt < 4; ++nt) acc[rg][nt] = (f32x4){0.f, 0.f, 0.f, 0.f};
        #pragma unroll
        for (int rg = 0; rg < 2; ++rg) {
            #pragma unroll
            for (int kt = 0; kt < 4; ++kt) {
                bf16x8 af = *(bf16x8*)&As[(rb + rg * 16 + l15) * LDA + kt * 32 + quad * 8];
                #pragma unroll
                for (int nt = 0; nt < 4; ++nt)
                    acc[rg][nt] = __builtin_amdgcn_mfma_f32_16x16x32_bf16(af, B2f[nt][kt], acc[rg][nt], 0, 0, 0);
            }
        }
        __syncthreads();   // all GEMM2 A-reads done before z overwrites As
        #pragma unroll
        for (int rg = 0; rg < 2; ++rg)
            #pragma unroll
            for (int nt = 0; nt < 4; ++nt) {
                int col = cg * 64 + nt * 16 + l15;
                int row0 = base + rb + rg * 16 + quad * 4;
                #pragma unroll
                for (int r = 0; r < 4; ++r) {
                    float z = acc[rg][nt][r] + b2r[nt];
                    if (row0 + r < N) { lsum[rg][nt] += z; lsq[rg][nt] = fmaf(z, z, lsq[rg][nt]); }
                    As[(rb + rg * 16 + quad * 4 + r) * LDA + col] = f2bf(z);
                }
            }
        __syncthreads();
        #pragma unroll
        for (int kk = 0; kk < 4; ++kk) {
            int i = tid + kk * 512;
            int row = (i * 8) >> 7, col = (i * 8) & 127;
            int rr = base + row;
            if (rr < N)
                *(bf16x8*)&dst[(size_t)rr * 128 + col] = *(bf16x8*)&As[row * LDA + col];
        }
    }
    #pragma unroll
    for (int nt = 0; nt < 4; ++nt) {
        int col = cg * 64 + nt * 16 + l15;
        atomicAdd(&sstat[col], lsum[0][nt] + lsum[1][nt]);
        atomicAdd(&sstat[128 + col], lsq[0][nt] + lsq[1][nt]);
    }
    __syncthreads();
    if (tid < 256) atomicAdd(&stats[tid], sstat[tid]);
}

// ---------------- fused layer-1 node MLP: 512 thr, reg-cached B ----------------
__global__ __launch_bounds__(512) void k_mlp1(
    const float* __restrict__ u28, const short* __restrict__ Wt1p,
    const float* __restrict__ b1, const short* __restrict__ Wt2,
    const float* __restrict__ b2, unsigned short* __restrict__ dst,
    float* __restrict__ stats, int N)
{
    __shared__ short Bs1[128 * 40];
    __shared__ short Bs2[128 * LDA];
    __shared__ short As[128 * LDA];
    __shared__ short A28[128 * 40];
    __shared__ float sstat[256];
    int tid = threadIdx.x;
    for (int i = tid; i < 128 * 32; i += 512) {
        int n = i >> 5, k = i & 31;
        Bs1[n * 40 + k] = Wt1p[i];
    }
    for (int i = tid; i < 2048; i += 512) {
        int n = (i * 8) >> 7, k = (i * 8) & 127;
        *(bf16x8*)&Bs2[n * LDA + k] = *(const bf16x8*)&Wt2[i * 8];
    }
    {
        int r = tid >> 2, c = tid & 3;
        if (r < 128) A28[r * 40 + 28 + c] = 0;
    }
    if (tid < 256) sstat[tid] = 0.f;
    int w = tid >> 6, lane = tid & 63;
    int l15 = lane & 15, quad = lane >> 4;
    int cg = w >> 2, rb = (w & 3) * 32;
    __syncthreads();

    bf16x8 B1f[4], B2f[4][4];
    float b1r[4], b2r[4];
    #pragma unroll
    for (int nt = 0; nt < 4; ++nt) {
        int col = cg * 64 + nt * 16 + l15;
        b1r[nt] = b1[col]; b2r[nt] = b2[col];
        B1f[nt] = *(bf16x8*)&Bs1[col * 40 + quad * 8];
        #pragma unroll
        for (int kt = 0; kt < 4; ++kt)
            B2f[nt][kt] = *(bf16x8*)&Bs2[col * LDA + kt * 32 + quad * 8];
    }
    float lsum[2][4], lsq[2][4];
    #pragma unroll
    for (int rg = 0; rg < 2; ++rg)
        #pragma unroll
        for (int nt = 0; nt < 4; ++nt) { lsum[rg][nt] = 0.f; lsq[rg][nt] = 0.f; }

    int numTiles = (N + 127) >> 7;
    for (int tile = blockIdx.x; tile < numTiles; tile += gridDim.x) {
        int base = tile * 128;
        __syncthreads();
        for (int i = tid; i < 128 * 28; i += 512) {
            int row = i / 28, col = i - row * 28;
            int rr = base + row;
            A28[row * 40 + col] = (rr < N) ? f2bf(u28[(size_t)rr * 28 + col]) : (short)0;
        }
        __syncthreads();
        f32x4 acc[2][4];
        #pragma unroll
        for (int rg = 0; rg < 2; ++rg)
            #pragma unroll
            for (int nt = 0; nt < 4; ++nt) acc[rg][nt] = (f32x4){0.f, 0.f, 0.f, 0.f};
        #pragma unroll
        for (int rg = 0; rg < 2; ++rg) {
            bf16x8 af = *(bf16x8*)&A28[(rb + rg * 16 + l15) * 40 + quad * 8];
            #pragma unroll
            for (int nt = 0; nt < 4; ++nt)
                acc[rg][nt] = __builtin_amdgcn_mfma_f32_16x16x32_bf16(af, B1f[nt], acc[rg][nt], 0, 0, 0);
        }
        // t -> As (A28 readers done: each wave reads only its own rows of A28;
        // but As may still be read by... first tile: As unwritten; later tiles guarded by loop-top sync)
        #pragma unroll
        for (int rg = 0; rg < 2; ++rg)
            #pragma unroll
            for (int nt = 0; nt < 4; ++nt) {
                int col = cg * 64 + nt * 16 + l15;
                #pragma unroll
                for (int r = 0; r < 4; ++r)
                    As[(rb + rg * 16 + quad * 4 + r) * LDA + col] =
                        f2bf(fmaxf(acc[rg][nt][r] + b1r[nt], 0.f));
            }
        __syncthreads();
        #pragma unroll
        for (int rg = 0; rg < 2; ++rg)
            #pragma unroll
            for (int nt = 0; nt < 4; ++nt) acc[rg][nt] = (f32x4){0.f, 0.f, 0.f, 0.f};
        #pragma unroll
        for (int rg = 0; rg < 2; ++rg) {
            #pragma unroll
            for (int kt = 0; kt < 4; ++kt) {
                bf16x8 af = *(bf16x8*)&As[(rb + rg * 16 + l15) * LDA + kt * 32 + quad * 8];
                #pragma unroll
                for (int nt = 0; nt < 4; ++nt)
                    acc[rg][nt] = __builtin_amdgcn_mfma_f32_16x16x32_bf16(af, B2f[nt][kt], acc[rg][nt], 0, 0, 0);
            }
        }
        __syncthreads();   // GEMM2 A-reads done before z overwrites As
        #pragma unroll
        for (int rg = 0; rg < 2; ++rg)
            #pragma unroll
            for (int nt = 0; nt < 4; ++nt) {
                int col = cg * 64 + nt * 16 + l15;
                int row0 = base + rb + rg * 16 + quad * 4;
                #pragma unroll
                for (int r = 0; r < 4; ++r) {
                    float z = acc[rg][nt][r] + b2r[nt];
                    if (row0 + r < N) { lsum[rg][nt] += z; lsq[rg][nt] = fmaf(z, z, lsq[rg][nt]); }
                    As[(rb + rg * 16 + quad * 4 + r) * LDA + col] = f2bf(z);
                }
            }
        __syncthreads();
        #pragma unroll
        for (int kk = 0; kk < 4; ++kk) {
            int i = tid + kk * 512;
            int row = (i * 8) >> 7, col = (i * 8) & 127;
            int rr = base + row;
            if (rr < N)
                *(bf16x8*)&dst[(size_t)rr * 128 + col] = *(bf16x8*)&As[row * LDA + col];
        }
    }
    #pragma unroll
    for (int nt = 0; nt < 4; ++nt) {
        int col = cg * 64 + nt * 16 + l15;
        atomicAdd(&sstat[col], lsum[0][nt] + lsum[1][nt]);
        atomicAdd(&sstat[128 + col], lsq[0][nt] + lsq[1][nt]);
    }
    __syncthreads();
    if (tid < 256) atomicAdd(&stats[tid], sstat[tid]);
}

// ---------------- stats -> scale/shift ----------------
__global__ __launch_bounds__(128) void k_stats(
    const float* __restrict__ stats, const float* __restrict__ g,
    const float* __restrict__ b, float* __restrict__ ss, float invN)
{
    int j = threadIdx.x;
    float mu  = stats[j] * invN;
    float var = fmaf(stats[128 + j], invN, -mu * mu);
    float sc  = rsqrtf(fmaxf(var, 0.f) + BNEPS) * g[j];
    ss[j] = sc;
    ss[128 + j] = fmaf(-mu, sc, b[j]);
}

// ---------------- BN-apply+relu(+residual), 16B lanes ----------------
__global__ __launch_bounds__(256) void k_bn(
    const unsigned short* __restrict__ z, const float* __restrict__ ss,
    unsigned short* __restrict__ h, int residual, int N)
{
    int idx8 = blockIdx.x * 256 + threadIdx.x;
    int stride = gridDim.x * 256;
    int c0 = (idx8 & 15) * 8;
    float scl[8], sht[8];
    #pragma unroll
    for (int r = 0; r < 8; ++r) { scl[r] = ss[c0 + r]; sht[r] = ss[128 + c0 + r]; }
    int total8 = N * 16;
    for (; idx8 < total8; idx8 += stride) {
        int n = idx8 >> 4;
        u16x8 z8 = *(const u16x8*)&z[(size_t)n * 128 + c0];
        float hn[8];
        #pragma unroll
        for (int r = 0; r < 8; ++r)
            hn[r] = fmaxf(fmaf(bf2f(z8[r]), scl[r], sht[r]), 0.f);
        if (residual) {
            u16x8 h8 = *(const u16x8*)&h[(size_t)n * 128 + c0];
            #pragma unroll
            for (int r = 0; r < 8; ++r) hn[r] += bf2f(h8[r]);
        }
        u16x8 o;
        #pragma unroll
        for (int r = 0; r < 8; ++r) o[r] = f2bfu(hn[r]);
        *(u16x8*)&h[(size_t)n * 128 + c0] = o;
    }
}

// ---------------- pool with fused last-layer BN+residual ----------------
__global__ __launch_bounds__(256) void k_poolbn(
    const unsigned short* __restrict__ z, const unsigned short* __restrict__ hprev,
    const float* __restrict__ ss, const int* __restrict__ offs2,
    const int* __restrict__ perm2, float* __restrict__ out, int S)
{
    int w = threadIdx.x >> 6, lane = threadIdx.x & 63;
    int s = blockIdx.x * 4 + w;
    if (s >= S) return;
    int c0 = lane * 2;
    float scl0 = ss[c0], scl1 = ss[c0 + 1];
    float sht0 = ss[128 + c0], sht1 = ss[128 + c0 + 1];
    int k0 = offs2[s], k1 = offs2[s + 1];
    float a0 = 0.f, a1 = 0.f;
    for (int k = k0; k < k1; ++k) {
        int n = perm2[k];
        ushort2 zv = *(const ushort2*)&z[(size_t)n * 128 + c0];
        ushort2 hv = *(const ushort2*)&hprev[(size_t)n * 128 + c0];
        a0 += fmaxf(fmaf(bf2f(zv.x), scl0, sht0), 0.f) + bf2f(hv.x);
        a1 += fmaxf(fmaf(bf2f(zv.y), scl1, sht1), 0.f) + bf2f(hv.y);
    }
    *(float2*)&out[(size_t)s * 128 + c0] = make_float2(a0, a1);
}

extern "C" void kernel_launch(void* const* d_in, const int* in_sizes, int n_in,
                              void* d_out, int out_size, void* d_ws, size_t ws_size,
                              hipStream_t stream) {
    const float* x    = (const float*)d_in[0];
    const int*   ei   = (const int*)d_in[1];
    const float* ea   = (const float*)d_in[2];
    const float* ew   = (const float*)d_in[3];
    const float* mask = (const float*)d_in[4];
    const int*   s2n  = (const int*)d_in[5];
    const float* be1W1 = (const float*)d_in[6];
    const float* be1b1 = (const float*)d_in[7];
    const float* be1W2 = (const float*)d_in[8];
    const float* be1b2 = (const float*)d_in[9];
    const float* m1W1  = (const float*)d_in[10];
    const float* m1b1  = (const float*)d_in[11];
    const float* m1W2  = (const float*)d_in[12];
    const float* m1b2  = (const float*)d_in[13];
    const float* bn1g  = (const float*)d_in[14];
    const float* bn1b  = (const float*)d_in[15];
    const float* eps1  = (const float*)d_in[16];
    const float* beW1  = (const float*)d_in[17];
    const float* beb1  = (const float*)d_in[18];
    const float* beW2  = (const float*)d_in[19];
    const float* beb2  = (const float*)d_in[20];
    const float* mW1   = (const float*)d_in[21];
    const float* mb1   = (const float*)d_in[22];
    const float* mW2   = (const float*)d_in[23];
    const float* mb2   = (const float*)d_in[24];
    const float* bng   = (const float*)d_in[25];
    const float* bnb   = (const float*)d_in[26];
    const float* epsL  = (const float*)d_in[27];

    const int N = in_sizes[0] / 28;
    const int E = in_sizes[1] / 2;
    const int S = out_size / 128;
    const float invN = 1.0f / (float)N;
    const int NS = N / 2;
    const int EMC = E / 2 + 8192;

    auto al16 = [](size_t v) { return (v + 15) & ~(size_t)15; };
    char* ws = (char*)d_ws;
    size_t offH      = 0;
    size_t offA0     = al16(offH + (size_t)N * 256);
    size_t offEm     = al16(offA0 + (size_t)N * 256);
    size_t emBytes   = (size_t)EMC * 256;
    if ((size_t)E * 56 > emBytes) emBytes = (size_t)E * 56;
    size_t offStats  = al16(offEm + emBytes);
    size_t offSS     = al16(offStats + 4096);
    size_t offWts    = al16(offSS + 1024);
    size_t offCounts = al16(offWts + 10 * 16384 * 2 + 4096 * 2 + 1024 * 2);
    size_t offOffs   = al16(offCounts + (size_t)N * 4);
    size_t offCursor = al16(offOffs + (size_t)(N + 1) * 4);
    size_t offPmeta  = al16(offCursor + (size_t)N * 4);
    size_t offPea    = al16(offPmeta + (size_t)E * 8);
    size_t offBsum   = al16(offPea + (size_t)E * 16);
    size_t offCnt2   = al16(offBsum + SCAN_NB * 4);
    size_t offOffs2  = al16(offCnt2 + (size_t)S * 4);
    size_t offCur2   = al16(offOffs2 + (size_t)(S + 1) * 4);
    size_t offPerm2  = al16(offCur2 + (size_t)S * 4);
    size_t need      = offPerm2 + (size_t)N * 4;
    if (ws_size < need) return;

    unsigned short* h    = (unsigned short*)(ws + offH);
    unsigned short* a0   = (unsigned short*)(ws + offA0);
    unsigned short* emsg = (unsigned short*)(ws + offEm);
    float* u28    = (float*)(ws + offA0);
    unsigned short* xbf = (unsigned short*)(ws + offA0 + 26214400);
    float* stats  = (float*)(ws + offStats);
    float* ssbuf  = (float*)(ws + offSS);
    short* wts    = (short*)(ws + offWts);
    short* w1p    = wts + 10 * 16384;
    short* w2p28  = w1p + 4096;
    int*   counts = (int*)(ws + offCounts);
    int*   offs   = (int*)(ws + offOffs);
    int*   cursor = (int*)(ws + offCursor);
    int2*  pmeta  = (int2*)(ws + offPmeta);
    float4* pea4  = (float4*)(ws + offPea);
    int*   bsum   = (int*)(ws + offBsum);
    int*   cnt2   = (int*)(ws + offCnt2);
    int*   offs2  = (int*)(ws + offOffs2);
    int*   cur2   = (int*)(ws + offCur2);
    int*   perm2  = (int*)(ws + offPerm2);
    const float4* ea4 = (const float4*)ea;

    hipMemsetAsync(stats, 0, 4 * 256 * sizeof(float), stream);
    hipMemsetAsync(counts, 0, (size_t)N * sizeof(int), stream);
    hipMemsetAsync(cnt2, 0, (size_t)S * sizeof(int), stream);

    k_prep<<<40, 256, 0, stream>>>(m1W2, beW2, mW1, mW2, wts);
    k_prep1<<<1, 256, 0, stream>>>(m1W1, w1p);
    k_prep28<<<1, 256, 0, stream>>>(be1W2, w2p28);
    k_prepx<<<512, 256, 0, stream>>>(x, xbf, N);

    // ---- edge CSR (dst-sorted; attrs pre-permuted) ----
    const int seg = (N + SCAN_NB - 1) / SCAN_NB;
    k_count<<<1024, 256, 0, stream>>>(ei, counts, E);
    k_scanA<<<SCAN_NB, 256, 0, stream>>>(counts, bsum, N, seg);
    k_scanB<<<1, 256, 0, stream>>>(bsum, SCAN_NB, offs, N);
    k_scanC<<<SCAN_NB, 256, 0, stream>>>(counts, bsum, offs, cursor, N, seg);
    k_scatter<<<1024, 256, 0, stream>>>(ei, ew, ea4, cursor, pmeta, pea4, E);

    // ---- segment CSR ----
    const int seg2 = (S + SCAN_NB - 1) / SCAN_NB;
    k_count2<<<512, 256, 0, stream>>>(s2n, mask, cnt2, N);
    k_scanA<<<SCAN_NB, 256, 0, stream>>>(cnt2, bsum, S, seg2);
    k_scanB<<<1, 256, 0, stream>>>(bsum, SCAN_NB, offs2, S);
    k_scanC<<<SCAN_NB, 256, 0, stream>>>(cnt2, bsum, offs2, cur2, S, seg2);
    k_scatter2<<<512, 256, 0, stream>>>(s2n, mask, cur2, perm2, N);

    auto wt_be = [&](int l) { return wts + (size_t)(1 + 3 * l + 0) * 16384; };
    auto wt_m1 = [&](int l) { return wts + (size_t)(1 + 3 * l + 1) * 16384; };
    auto wt_m2 = [&](int l) { return wts + (size_t)(1 + 3 * l + 2) * 16384; };

    // ---- layer 1 (28 -> 128) ----
    k_emsg28_mm<<<2048, 256, 0, stream>>>(pea4, be1W1, be1b1, w2p28, be1b2, emsg, E);
    k_gather28<<<(N + 7) / 8, 256, 0, stream>>>(x, xbf, offs, pmeta, emsg, eps1, u28, N);
    k_mlp1<<<512, 512, 0, stream>>>(u28, w1p, m1b1, wts /*m1W2t*/, m1b2, h, stats, N);
    k_stats<<<1, 128, 0, stream>>>(stats, bn1g, bn1b, ssbuf, invN);
    k_bn<<<2048, 256, 0, stream>>>(h, ssbuf, h, 0, N);

    // ---- layers 2..4 (node-range chunks) ----
    for (int l = 0; l < 3; ++l) {
        for (int c = 0; c < 2; ++c) {
            int n0 = (c == 0) ? 0 : NS;
            int n1 = (c == 0) ? NS : N;
            k_emsg<<<2048, 256, 0, stream>>>(pea4,
                beW1 + (size_t)l * 512, beb1 + (size_t)l * 128,
                wt_be(l), beb2 + (size_t)l * 128, emsg, offs, n0, n1);
            k_gather<<<(n1 - n0 + 7) / 8, 256, 0, stream>>>(h, offs, pmeta, emsg, a0,
                epsL, l, n0, n1);
        }
        k_mlp<<<512, 512, 0, stream>>>(a0, wt_m1(l), mb1 + (size_t)l * 128,
                                       wt_m2(l), mb2 + (size_t)l * 128, a0,
                                       stats + 256 * (l + 1), N);
        k_stats<<<1, 128, 0, stream>>>(stats + 256 * (l + 1),
            bng + (size_t)l * 128, bnb + (size_t)l * 128, ssbuf, invN);
        if (l < 2) {
            k_bn<<<2048, 256, 0, stream>>>(a0, ssbuf, h, 1, N);
        }
    }

    // ---- pool with fused layer-4 BN+residual ----
    k_poolbn<<<(S + 3) / 4, 256, 0, stream>>>(a0, h, ssbuf, offs2, perm2,
                                              (float*)d_out, S);
}